// Round 2
// baseline (2077.296 us; speedup 1.0000x reference)
//
#include <hip/hip_runtime.h>

#define B 4096
#define T 2048
#define H 64
#define NBATCH 8
#define NB (B / NBATCH)     // 512 blocks -> 2 blocks/CU (anti-phase barrier groups)
#define NTHREADS 512        // 8 waves/block -> 2/SIMD; 4/SIMD with 2 blocks resident

typedef __attribute__((ext_vector_type(8))) short short8;
typedef __attribute__((ext_vector_type(4))) float f32x4;

__device__ __forceinline__ float ex2(float x) { return __builtin_amdgcn_exp2f(x); }
__device__ __forceinline__ float sigm(float x) {
    return __builtin_amdgcn_rcpf(1.0f + ex2(-1.4426950408889634f * x));
}
// tanh(x) = 2*sigmoid(2x)-1 : 5 ops, saturates correctly at +-inf, no clamp.
__device__ __forceinline__ float tanh_(float x) {
    return __builtin_fmaf(2.0f,
        __builtin_amdgcn_rcpf(1.0f + ex2(-2.8853900817779268f * x)), -1.0f);
}
__device__ __forceinline__ unsigned short f2bf(float f) {  // RNE f32->bf16
    unsigned u = __builtin_bit_cast(unsigned, f);
    u += 0x7fffu + ((u >> 16) & 1u);
    return (unsigned short)(u >> 16);
}
// LDS-only barrier: drain lgkm (ds ops) but leave global loads in flight.
__device__ __forceinline__ void lds_barrier() {
    asm volatile("s_waitcnt lgkmcnt(0)\n\ts_barrier" ::: "memory");
}

// ---------------------------------------------------------------------------
// Encoder: 512 blocks x 512 threads (8 waves), 8 batches/block, 1 cell/lane.
// Wave w owns units w*8..w*8+7 as TWO 16-row MFMA tiles (rt=0: units w*8..+3,
// rt=1: units w*8+4..+7). B-operand columns duplicate batches mod 8, so tile
// rt's C at (lo,hi) = gates of unit w*8+rt*4+hi, batch lo&7. Lane keeps the
// tile matching lo>=8. Two blocks/CU -> barrier stalls of one block are
// filled by the other block's waves on the same SIMDs.
// ---------------------------------------------------------------------------
extern "C" __global__ void __launch_bounds__(NTHREADS, 4)
enc_kernel(const float* __restrict__ padded, const int* __restrict__ seq_len,
           const float* __restrict__ Wih, const float* __restrict__ Whh,
           const float* __restrict__ bias,
           float* __restrict__ h_out, float* __restrict__ c_out)
{
    __shared__ unsigned short hA[2][NBATCH][72];
    __shared__ int slen[NBATCH];

    const int tid = threadIdx.x;
    const int w = tid >> 6, L = tid & 63, lo = L & 15, hi = L >> 4;
    const int b0 = blockIdx.x * NBATCH;
    const int bat = lo & 7;
    const bool hiT = lo >= 8;                 // lane's cell lives in row-tile 1
    const int unit = w * 8 + (hiT ? 4 : 0) + hi;

    // A-frags for both row-tiles: remapped rows G(m,rt) = (m&3)*64 + w*8+rt*4 + (m>>2)
    short8 af[2][2];
    #pragma unroll
    for (int rt = 0; rt < 2; ++rt) {
        const int G = (lo & 3) * 64 + w * 8 + rt * 4 + (lo >> 2);
        #pragma unroll
        for (int kk = 0; kk < 2; ++kk) {
            const float* src = Whh + (long)G * H + kk * 32 + hi * 8;
            short8 f;
            #pragma unroll
            for (int j = 0; j < 8; ++j) f[j] = (short)f2bf(src[j]);
            af[rt][kk] = f;
        }
    }
    // z-init coefficients for BOTH tiles (C row hi*4+r of tile rt = gate r of
    // unit w*8+rt*4+hi, col = batch lo&7)
    float b_g[2][4], wi_g[2][4];
    #pragma unroll
    for (int rt = 0; rt < 2; ++rt)
        #pragma unroll
        for (int r = 0; r < 4; ++r) {
            const int G2 = r * 64 + w * 8 + rt * 4 + hi;
            b_g[rt][r] = bias[G2];
            wi_g[rt][r] = Wih[G2];
        }

    hA[0][tid >> 6][tid & 63] = 0;            // 512 threads cover [8][64]
    if (tid < NBATCH) slen[tid] = seq_len[b0 + tid];
    lds_barrier();

    int maxlen = 1;
    #pragma unroll
    for (int i = 0; i < NBATCH; ++i) maxlen = max(maxlen, slen[i]);
    const int len_lo = slen[bat];

    const float* xrow = padded + (long)(b0 + bat) * T;
    f32x4 xc = *(const f32x4*)(xrow);
    f32x4 xn = *(const f32x4*)(xrow + 4);

    float c_st = 0.f, h_st = 0.f;

#define ESTEP(P, XI)                                                          \
    {                                                                         \
        const float x = xc[XI];                                               \
        short8 hb0 = *(const short8*)&hA[P][bat][hi * 8];                     \
        short8 hb1 = *(const short8*)&hA[P][bat][32 + hi * 8];                \
        f32x4 z0 = {b_g[0][0] + wi_g[0][0] * x, b_g[0][1] + wi_g[0][1] * x,   \
                    b_g[0][2] + wi_g[0][2] * x, b_g[0][3] + wi_g[0][3] * x};  \
        f32x4 z1 = {b_g[1][0] + wi_g[1][0] * x, b_g[1][1] + wi_g[1][1] * x,   \
                    b_g[1][2] + wi_g[1][2] * x, b_g[1][3] + wi_g[1][3] * x};  \
        z0 = __builtin_amdgcn_mfma_f32_16x16x32_bf16(af[0][0], hb0, z0, 0,0,0); \
        z1 = __builtin_amdgcn_mfma_f32_16x16x32_bf16(af[1][0], hb0, z1, 0,0,0); \
        z0 = __builtin_amdgcn_mfma_f32_16x16x32_bf16(af[0][1], hb1, z0, 0,0,0); \
        z1 = __builtin_amdgcn_mfma_f32_16x16x32_bf16(af[1][1], hb1, z1, 0,0,0); \
        const bool act = (t + XI) < len_lo;                                   \
        const float a0 = hiT ? z1[0] : z0[0];                                 \
        const float a1 = hiT ? z1[1] : z0[1];                                 \
        const float a2 = hiT ? z1[2] : z0[2];                                 \
        const float a3 = hiT ? z1[3] : z0[3];                                 \
        float i_ = sigm(a0);                                                  \
        float f_ = sigm(a1);                                                  \
        float g_ = tanh_(a2);                                                 \
        float o_ = sigm(a3);                                                  \
        float cn = f_ * c_st + i_ * g_;                                       \
        float hn = o_ * tanh_(cn);                                            \
        if (act) { c_st = cn; h_st = hn; }                                    \
        hA[(P) ^ 1][bat][unit] = f2bf(h_st);                                  \
        lds_barrier();                                                        \
    }

    for (int t = 0; t < maxlen; t += 4) {
        int nb = t + 8; if (nb > T - 4) nb = T - 4;
        f32x4 xf = *(const f32x4*)(xrow + nb);   // 8-step-ahead prefetch
        ESTEP(0, 0) ESTEP(1, 1) ESTEP(0, 2) ESTEP(1, 3)
        xc = xn; xn = xf;
    }
#undef ESTEP

    h_out[(long)(b0 + bat) * H + unit] = h_st;
    c_out[(long)(b0 + bat) * H + unit] = c_st;
}

// ---------------------------------------------------------------------------
// Bottleneck + y0 correction term for the decoder's rank-1 fold.
// ---------------------------------------------------------------------------
extern "C" __global__ void __launch_bounds__(256)
mid_kernel(const float* __restrict__ h_enc,
           const float* __restrict__ eW, const float* __restrict__ eb,
           const float* __restrict__ dW, const float* __restrict__ db,
           const float* __restrict__ outW, const float* __restrict__ outb,
           float* __restrict__ hz_out, float* __restrict__ hd_out,
           float* __restrict__ y0c)
{
    int b = blockIdx.x * blockDim.x + threadIdx.x;
    if (b >= B) return;
    const float* h = h_enc + (long)b * H;
    float hz[3];
    #pragma unroll
    for (int j = 0; j < 3; ++j) {
        float s = eb[j];
        for (int k = 0; k < H; ++k) s += h[k] * eW[j*H + k];
        hz[j] = sigm(s);
        hz_out[b*3 + j] = hz[j];
    }
    float y0 = outb[0];
    for (int u = 0; u < H; ++u) {
        float hd = db[u] + hz[0]*dW[u*3] + hz[1]*dW[u*3+1] + hz[2]*dW[u*3+2];
        hd_out[(long)b*H + u] = hd;
        y0 += outW[u] * hd;
    }
    y0c[b] = y0;
}

// ---------------------------------------------------------------------------
// Decoder: rank-1 fold (W' = Whh + Wih (x) outW, b' = b + Wih*outb) -> pure
// LSTM. Same 8-batch / 8-wave / dual-tile structure as the encoder.
// y_{t-1} recovered via 2 extra MFMAs rotating across waves (w==t&7),
// one step delayed. t=0 correction peeled.
// ---------------------------------------------------------------------------
extern "C" __global__ void __launch_bounds__(NTHREADS, 4)
dec_kernel(const float* __restrict__ hd, const float* __restrict__ c_in,
           const float* __restrict__ Wih, const float* __restrict__ Whh,
           const float* __restrict__ bias, const float* __restrict__ outW,
           const float* __restrict__ outb, const float* __restrict__ y0c,
           float* __restrict__ y_out)
{
    __shared__ unsigned short hA[2][NBATCH][72];

    const int tid = threadIdx.x;
    const int w = tid >> 6, L = tid & 63, lo = L & 15, hi = L >> 4;
    const int b0 = blockIdx.x * NBATCH;
    const int bat = lo & 7;
    const bool hiT = lo >= 8;
    const int unit = w * 8 + (hiT ? 4 : 0) + hi;

    short8 af[2][2];
    #pragma unroll
    for (int rt = 0; rt < 2; ++rt) {
        const int G = (lo & 3) * 64 + w * 8 + rt * 4 + (lo >> 2);
        const float wir = Wih[G];
        #pragma unroll
        for (int kk = 0; kk < 2; ++kk) {
            const float* src = Whh + (long)G * H + kk * 32 + hi * 8;
            const float* ow  = outW + kk * 32 + hi * 8;
            short8 f;
            #pragma unroll
            for (int j = 0; j < 8; ++j) f[j] = (short)f2bf(src[j] + wir * ow[j]);
            af[rt][kk] = f;
        }
    }
    const float outb_s = outb[0];
    const float y0 = y0c[b0 + bat];
    float zb[2][4];
    #pragma unroll
    for (int rt = 0; rt < 2; ++rt)
        #pragma unroll
        for (int r = 0; r < 4; ++r) {
            const int G2 = r * 64 + w * 8 + rt * 4 + hi;
            zb[rt][r] = bias[G2] + Wih[G2] * outb_s;
        }
    float corr[4];
    #pragma unroll
    for (int r = 0; r < 4; ++r)
        corr[r] = Wih[r * 64 + unit] * y0;

    short8 ya[2];   // y-extraction A-frag: row 0 = outW, rows 1..15 = 0
    #pragma unroll
    for (int kk = 0; kk < 2; ++kk) {
        short8 f = (short8)0;
        if (lo == 0)
            #pragma unroll
            for (int j = 0; j < 8; ++j) f[j] = (short)f2bf(outW[kk*32 + hi*8 + j]);
        ya[kk] = f;
    }

    hA[0][tid >> 6][tid & 63] = f2bf(hd[(long)(b0 + (tid >> 6)) * H + (tid & 63)]);
    float c_st = c_in[(long)(b0 + bat) * H + unit];
    lds_barrier();

#define DSTEP(P, CORR, TT)                                                    \
    {                                                                         \
        short8 hb0 = *(const short8*)&hA[P][bat][hi * 8];                     \
        short8 hb1 = *(const short8*)&hA[P][bat][32 + hi * 8];                \
        f32x4 z0 = {zb[0][0], zb[0][1], zb[0][2], zb[0][3]};                  \
        f32x4 z1 = {zb[1][0], zb[1][1], zb[1][2], zb[1][3]};                  \
        z0 = __builtin_amdgcn_mfma_f32_16x16x32_bf16(af[0][0], hb0, z0, 0,0,0); \
        z1 = __builtin_amdgcn_mfma_f32_16x16x32_bf16(af[1][0], hb0, z1, 0,0,0); \
        z0 = __builtin_amdgcn_mfma_f32_16x16x32_bf16(af[0][1], hb1, z0, 0,0,0); \
        z1 = __builtin_amdgcn_mfma_f32_16x16x32_bf16(af[1][1], hb1, z1, 0,0,0); \
        if (w == ((TT) & 7)) {  /* y_{t-1} = outW.h_{t-1}+outb, rotated */    \
            f32x4 zy = {outb_s, outb_s, outb_s, outb_s};                      \
            zy = __builtin_amdgcn_mfma_f32_16x16x32_bf16(ya[0], hb0, zy, 0,0,0); \
            zy = __builtin_amdgcn_mfma_f32_16x16x32_bf16(ya[1], hb1, zy, 0,0,0); \
            if ((TT) > 0 && hi == 0 && lo < 8)                                \
                y_out[(long)(b0 + lo) * T + ((TT) - 1)] = zy[0];              \
        }                                                                     \
        float a0 = hiT ? z1[0] : z0[0];                                       \
        float a1 = hiT ? z1[1] : z0[1];                                       \
        float a2 = hiT ? z1[2] : z0[2];                                       \
        float a3 = hiT ? z1[3] : z0[3];                                       \
        if (CORR) { a0 -= corr[0]; a1 -= corr[1]; a2 -= corr[2]; a3 -= corr[3]; } \
        float i_ = sigm(a0);                                                  \
        float f_ = sigm(a1);                                                  \
        float g_ = tanh_(a2);                                                 \
        float o_ = sigm(a3);                                                  \
        float cn = f_ * c_st + i_ * g_;                                       \
        float hn = o_ * tanh_(cn);                                            \
        c_st = cn;                                                            \
        hA[(P) ^ 1][bat][unit] = f2bf(hn);                                    \
        lds_barrier();                                                        \
    }

    DSTEP(0, 1, 0) DSTEP(1, 0, 1) DSTEP(0, 0, 2) DSTEP(1, 0, 3)
    for (int t = 4; t < T; t += 4) {
        DSTEP(0, 0, t) DSTEP(1, 0, t + 1) DSTEP(0, 0, t + 2) DSTEP(1, 0, t + 3)
    }
#undef DSTEP

    if (w == 0) {       // final y_{T-1} (T even -> parity 0)
        short8 hb0 = *(const short8*)&hA[0][bat][hi * 8];
        short8 hb1 = *(const short8*)&hA[0][bat][32 + hi * 8];
        f32x4 zy = {outb_s, outb_s, outb_s, outb_s};
        zy = __builtin_amdgcn_mfma_f32_16x16x32_bf16(ya[0], hb0, zy, 0,0,0);
        zy = __builtin_amdgcn_mfma_f32_16x16x32_bf16(ya[1], hb1, zy, 0,0,0);
        if (hi == 0 && lo < 8) y_out[(long)(b0 + lo) * T + (T - 1)] = zy[0];
    }
}

// ---------------------------------------------------------------------------
extern "C" __global__ void __launch_bounds__(256)
loss_kernel(const float* __restrict__ padded, const float* __restrict__ y,
            const int* __restrict__ seq_len, float* __restrict__ acc2)
{
    const long n4 = (long)B * T / 4;
    long i0 = (long)(blockIdx.x * blockDim.x + threadIdx.x);
    long stride = (long)gridDim.x * blockDim.x;
    float s = 0.f, cnt = 0.f;
    for (long i = i0; i < n4; i += stride) {
        int b = (int)(i >> 9);                  // T/4 = 512
        int t = (int)(i & 511) * 4;
        int len = seq_len[b];
        f32x4 pv = *(const f32x4*)&padded[i * 4];
        f32x4 yv = *(const f32x4*)&y[i * 4];
        #pragma unroll
        for (int e = 0; e < 4; ++e)
            if (t + e < len) { float d = pv[e] - yv[e]; s += d * d; cnt += 1.0f; }
    }
    for (int m = 1; m < 64; m <<= 1) { s += __shfl_xor(s, m); cnt += __shfl_xor(cnt, m); }
    if ((threadIdx.x & 63) == 0) { atomicAdd(&acc2[0], s); atomicAdd(&acc2[1], cnt); }
}

extern "C" __global__ void fin_kernel(const float* __restrict__ acc2, float* __restrict__ out)
{
    out[0] = acc2[0] / acc2[1];
}

// ---------------------------------------------------------------------------
extern "C" void kernel_launch(void* const* d_in, const int* in_sizes, int n_in,
                              void* d_out, int out_size, void* d_ws, size_t ws_size,
                              hipStream_t stream)
{
    const float* padded = (const float*)d_in[0];
    const int*   seq    = (const int*)  d_in[1];
    const float* eWih   = (const float*)d_in[2];
    const float* eWhh   = (const float*)d_in[3];
    const float* eb     = (const float*)d_in[4];
    const float* elW    = (const float*)d_in[5];
    const float* elb    = (const float*)d_in[6];
    const float* dlW    = (const float*)d_in[7];
    const float* dlb    = (const float*)d_in[8];
    const float* dWih   = (const float*)d_in[9];
    const float* dWhh   = (const float*)d_in[10];
    const float* db     = (const float*)d_in[11];
    const float* outW   = (const float*)d_in[12];
    const float* outb   = (const float*)d_in[13];
    float* out = (float*)d_out;

    float* ws    = (float*)d_ws;
    float* h_enc = ws;
    float* c_enc = ws + (long)B * H;
    float* hd    = ws + 2L * B * H;
    float* y0c   = ws + 3L * B * H;
    float* acc2  = ws + 3L * B * H + B;

    float* out_pad = out + 1;
    float* out_y   = out + 1 + (long)B * T;
    float* out_hz  = out + 1 + 2L * (long)B * T;

    hipMemcpyAsync(out_pad, padded, (long)B * T * sizeof(float),
                   hipMemcpyDeviceToDevice, stream);
    hipMemsetAsync(acc2, 0, 2 * sizeof(float), stream);

    enc_kernel<<<NB, NTHREADS, 0, stream>>>(padded, seq, eWih, eWhh, eb, h_enc, c_enc);
    mid_kernel<<<B / 256, 256, 0, stream>>>(h_enc, elW, elb, dlW, dlb, outW, outb,
                                            out_hz, hd, y0c);
    dec_kernel<<<NB, NTHREADS, 0, stream>>>(hd, c_enc, dWih, dWhh, db, outW, outb, y0c, out_y);
    loss_kernel<<<1024, 256, 0, stream>>>(padded, out_y, seq, acc2);
    fin_kernel<<<1, 1, 0, stream>>>(acc2, out);
}

// Round 3
// 1827.864 us; speedup vs baseline: 1.1365x; 1.1365x over previous
//
#include <hip/hip_runtime.h>

#define B 4096
#define T 2048
#define H 64
#define NBATCH 16
#define NB (B / NBATCH)     // 256 blocks -> 1 per CU
#define NTHREADS 512        // 8 waves -> 2 waves/SIMD, 2 cells/lane (dual-tile)

typedef __attribute__((ext_vector_type(8))) short short8;
typedef __attribute__((ext_vector_type(4))) float f32x4;

__device__ __forceinline__ float ex2(float x) { return __builtin_amdgcn_exp2f(x); }
__device__ __forceinline__ float sigm(float x) {
    return __builtin_amdgcn_rcpf(1.0f + ex2(-1.4426950408889634f * x));
}
// tanh(x) = 2*sigmoid(2x)-1 : 5 ops, saturates correctly at +-inf, no clamp.
__device__ __forceinline__ float tanh_(float x) {
    return __builtin_fmaf(2.0f,
        __builtin_amdgcn_rcpf(1.0f + ex2(-2.8853900817779268f * x)), -1.0f);
}
__device__ __forceinline__ unsigned short f2bf(float f) {  // RNE f32->bf16
    unsigned u = __builtin_bit_cast(unsigned, f);
    u += 0x7fffu + ((u >> 16) & 1u);
    return (unsigned short)(u >> 16);
}
// Pack two f32 -> two bf16 (RNE) in one instruction (T12 recipe).
__device__ __forceinline__ unsigned pk_bf16(float a, float b) {
    unsigned r;
    asm("v_cvt_pk_bf16_f32 %0, %1, %2" : "=v"(r) : "v"(a), "v"(b));
    return r;
}
// LDS-only barrier: drain lgkm (ds ops) but leave global loads in flight.
__device__ __forceinline__ void lds_barrier() {
    asm volatile("s_waitcnt lgkmcnt(0)\n\ts_barrier" ::: "memory");
}

// ---------------------------------------------------------------------------
// Encoder: 256 blocks x 512 threads (8 waves), 16 batches/block, 2 cells/lane.
// Wave w owns units w*8..w*8+7 as TWO 16-row MFMA tiles sharing one B-frag
// (16 batch columns). Lane (lo,hi): cell A = (batch lo, unit w*8+hi) from z0,
// cell B = (batch lo, unit w*8+4+hi) from z1 -- both MFMA quads fully used.
// 8-wave barrier, halved LDS reads vs 16-wave/1-cell layout; 2 independent
// activation chains per wave hide transcendental latency.
// ---------------------------------------------------------------------------
extern "C" __global__ void __launch_bounds__(NTHREADS, 2)
enc_kernel(const float* __restrict__ padded, const int* __restrict__ seq_len,
           const float* __restrict__ Wih, const float* __restrict__ Whh,
           const float* __restrict__ bias,
           float* __restrict__ h_out, float* __restrict__ c_out)
{
    __shared__ unsigned short hX[2][NBATCH][72];
    __shared__ int slen[NBATCH];

    const int tid = threadIdx.x;
    const int w = tid >> 6, L = tid & 63, lo = L & 15, hi = L >> 4;
    const int b0 = blockIdx.x * NBATCH;
    const int unitA = w * 8 + hi;          // row-tile 0
    const int unitB = w * 8 + 4 + hi;      // row-tile 1

    // A-frags, remapped rows G(m,rt) = (m&3)*64 + w*8+rt*4 + (m>>2)
    short8 af[2][2];
    #pragma unroll
    for (int rt = 0; rt < 2; ++rt) {
        const int G = (lo & 3) * 64 + w * 8 + rt * 4 + (lo >> 2);
        #pragma unroll
        for (int kk = 0; kk < 2; ++kk) {
            const float* src = Whh + (long)G * H + kk * 32 + hi * 8;
            short8 f;
            #pragma unroll
            for (int j = 0; j < 8; ++j) f[j] = (short)f2bf(src[j]);
            af[rt][kk] = f;
        }
    }
    // C row hi*4+r of tile rt = gate r of unit w*8+rt*4+hi, col = batch lo
    float b_g[2][4], wi_g[2][4];
    #pragma unroll
    for (int rt = 0; rt < 2; ++rt)
        #pragma unroll
        for (int r = 0; r < 4; ++r) {
            const int G2 = r * 64 + w * 8 + rt * 4 + hi;
            b_g[rt][r] = bias[G2];
            wi_g[rt][r] = Wih[G2];
        }

    #pragma unroll
    for (int idx = tid; idx < NBATCH * 64; idx += NTHREADS)
        hX[0][idx >> 6][idx & 63] = 0;
    if (tid < NBATCH) slen[tid] = seq_len[b0 + tid];
    lds_barrier();

    int maxlen = 1;
    #pragma unroll
    for (int i = 0; i < NBATCH; ++i) maxlen = max(maxlen, slen[i]);
    const int len_lo = slen[lo];

    const float* xrow = padded + (long)(b0 + lo) * T;
    f32x4 xc = *(const f32x4*)(xrow);
    f32x4 xn = *(const f32x4*)(xrow + 4);

    float csA = 0.f, hsA = 0.f, csB = 0.f, hsB = 0.f;

#define ESTEP(P, XI)                                                          \
    {                                                                         \
        const float x = xc[XI];                                               \
        short8 hb0 = *(const short8*)&hX[P][lo][hi * 8];                      \
        short8 hb1 = *(const short8*)&hX[P][lo][32 + hi * 8];                 \
        f32x4 z0 = {b_g[0][0] + wi_g[0][0] * x, b_g[0][1] + wi_g[0][1] * x,   \
                    b_g[0][2] + wi_g[0][2] * x, b_g[0][3] + wi_g[0][3] * x};  \
        f32x4 z1 = {b_g[1][0] + wi_g[1][0] * x, b_g[1][1] + wi_g[1][1] * x,   \
                    b_g[1][2] + wi_g[1][2] * x, b_g[1][3] + wi_g[1][3] * x};  \
        z0 = __builtin_amdgcn_mfma_f32_16x16x32_bf16(af[0][0], hb0, z0, 0,0,0); \
        z1 = __builtin_amdgcn_mfma_f32_16x16x32_bf16(af[1][0], hb0, z1, 0,0,0); \
        z0 = __builtin_amdgcn_mfma_f32_16x16x32_bf16(af[0][1], hb1, z0, 0,0,0); \
        z1 = __builtin_amdgcn_mfma_f32_16x16x32_bf16(af[1][1], hb1, z1, 0,0,0); \
        const bool act = (t + XI) < len_lo;                                   \
        float iA = sigm(z0[0]), fA = sigm(z0[1]);                             \
        float gA = tanh_(z0[2]), oA = sigm(z0[3]);                            \
        float iB = sigm(z1[0]), fB = sigm(z1[1]);                             \
        float gB = tanh_(z1[2]), oB = sigm(z1[3]);                            \
        float cnA = fA * csA + iA * gA;                                       \
        float cnB = fB * csB + iB * gB;                                       \
        float hnA = oA * tanh_(cnA);                                          \
        float hnB = oB * tanh_(cnB);                                          \
        if (act) { csA = cnA; hsA = hnA; csB = cnB; hsB = hnB; }              \
        unsigned up = pk_bf16(hsA, hsB);                                      \
        hX[(P) ^ 1][lo][unitA] = (unsigned short)up;                          \
        hX[(P) ^ 1][lo][unitB] = (unsigned short)(up >> 16);                  \
        lds_barrier();                                                        \
    }

    for (int t = 0; t < maxlen; t += 4) {
        int nb = t + 8; if (nb > T - 4) nb = T - 4;
        f32x4 xf = *(const f32x4*)(xrow + nb);   // 8-step-ahead prefetch
        ESTEP(0, 0) ESTEP(1, 1) ESTEP(0, 2) ESTEP(1, 3)
        xc = xn; xn = xf;
    }
#undef ESTEP

    h_out[(long)(b0 + lo) * H + unitA] = hsA;
    h_out[(long)(b0 + lo) * H + unitB] = hsB;
    c_out[(long)(b0 + lo) * H + unitA] = csA;
    c_out[(long)(b0 + lo) * H + unitB] = csB;
}

// ---------------------------------------------------------------------------
// Bottleneck + y0 correction term for the decoder's rank-1 fold.
// ---------------------------------------------------------------------------
extern "C" __global__ void __launch_bounds__(256)
mid_kernel(const float* __restrict__ h_enc,
           const float* __restrict__ eW, const float* __restrict__ eb,
           const float* __restrict__ dW, const float* __restrict__ db,
           const float* __restrict__ outW, const float* __restrict__ outb,
           float* __restrict__ hz_out, float* __restrict__ hd_out,
           float* __restrict__ y0c)
{
    int b = blockIdx.x * blockDim.x + threadIdx.x;
    if (b >= B) return;
    const float* h = h_enc + (long)b * H;
    float hz[3];
    #pragma unroll
    for (int j = 0; j < 3; ++j) {
        float s = eb[j];
        for (int k = 0; k < H; ++k) s += h[k] * eW[j*H + k];
        hz[j] = sigm(s);
        hz_out[b*3 + j] = hz[j];
    }
    float y0 = outb[0];
    for (int u = 0; u < H; ++u) {
        float hd = db[u] + hz[0]*dW[u*3] + hz[1]*dW[u*3+1] + hz[2]*dW[u*3+2];
        hd_out[(long)b*H + u] = hd;
        y0 += outW[u] * hd;
    }
    y0c[b] = y0;
}

// ---------------------------------------------------------------------------
// Decoder: rank-1 fold (W' = Whh + Wih (x) outW, b' = b + Wih*outb) -> pure
// LSTM. Same 16-batch / 8-wave / dual-tile / 2-cells-per-lane structure as
// the encoder. y_{t-1} recovered via 2 extra MFMAs rotating across waves
// (w==t&7), one step delayed. t=0 correction peeled.
// ---------------------------------------------------------------------------
extern "C" __global__ void __launch_bounds__(NTHREADS, 2)
dec_kernel(const float* __restrict__ hd, const float* __restrict__ c_in,
           const float* __restrict__ Wih, const float* __restrict__ Whh,
           const float* __restrict__ bias, const float* __restrict__ outW,
           const float* __restrict__ outb, const float* __restrict__ y0c,
           float* __restrict__ y_out)
{
    __shared__ unsigned short hX[2][NBATCH][72];

    const int tid = threadIdx.x;
    const int w = tid >> 6, L = tid & 63, lo = L & 15, hi = L >> 4;
    const int b0 = blockIdx.x * NBATCH;
    const int unitA = w * 8 + hi;
    const int unitB = w * 8 + 4 + hi;

    short8 af[2][2];
    #pragma unroll
    for (int rt = 0; rt < 2; ++rt) {
        const int G = (lo & 3) * 64 + w * 8 + rt * 4 + (lo >> 2);
        const float wir = Wih[G];
        #pragma unroll
        for (int kk = 0; kk < 2; ++kk) {
            const float* src = Whh + (long)G * H + kk * 32 + hi * 8;
            const float* ow  = outW + kk * 32 + hi * 8;
            short8 f;
            #pragma unroll
            for (int j = 0; j < 8; ++j) f[j] = (short)f2bf(src[j] + wir * ow[j]);
            af[rt][kk] = f;
        }
    }
    const float outb_s = outb[0];
    const float y0 = y0c[b0 + lo];
    float zb[2][4], corr[2][4];
    #pragma unroll
    for (int rt = 0; rt < 2; ++rt)
        #pragma unroll
        for (int r = 0; r < 4; ++r) {
            const int G2 = r * 64 + w * 8 + rt * 4 + hi;
            zb[rt][r] = bias[G2] + Wih[G2] * outb_s;
            corr[rt][r] = Wih[G2] * y0;
        }

    short8 ya[2];   // y-extraction A-frag: row 0 = outW, rows 1..15 = 0
    #pragma unroll
    for (int kk = 0; kk < 2; ++kk) {
        short8 f = (short8)0;
        if (lo == 0)
            #pragma unroll
            for (int j = 0; j < 8; ++j) f[j] = (short)f2bf(outW[kk*32 + hi*8 + j]);
        ya[kk] = f;
    }

    #pragma unroll
    for (int idx = tid; idx < NBATCH * 64; idx += NTHREADS)
        hX[0][idx >> 6][idx & 63] = f2bf(hd[(long)(b0 + (idx >> 6)) * H + (idx & 63)]);
    float csA = c_in[(long)(b0 + lo) * H + unitA];
    float csB = c_in[(long)(b0 + lo) * H + unitB];
    lds_barrier();

#define DSTEP(P, CORR, TT)                                                    \
    {                                                                         \
        short8 hb0 = *(const short8*)&hX[P][lo][hi * 8];                      \
        short8 hb1 = *(const short8*)&hX[P][lo][32 + hi * 8];                 \
        f32x4 z0 = {zb[0][0], zb[0][1], zb[0][2], zb[0][3]};                  \
        f32x4 z1 = {zb[1][0], zb[1][1], zb[1][2], zb[1][3]};                  \
        z0 = __builtin_amdgcn_mfma_f32_16x16x32_bf16(af[0][0], hb0, z0, 0,0,0); \
        z1 = __builtin_amdgcn_mfma_f32_16x16x32_bf16(af[1][0], hb0, z1, 0,0,0); \
        z0 = __builtin_amdgcn_mfma_f32_16x16x32_bf16(af[0][1], hb1, z0, 0,0,0); \
        z1 = __builtin_amdgcn_mfma_f32_16x16x32_bf16(af[1][1], hb1, z1, 0,0,0); \
        if (w == ((TT) & 7)) {  /* y_{t-1} = outW.h_{t-1}+outb, rotated */    \
            f32x4 zy = {outb_s, outb_s, outb_s, outb_s};                      \
            zy = __builtin_amdgcn_mfma_f32_16x16x32_bf16(ya[0], hb0, zy, 0,0,0); \
            zy = __builtin_amdgcn_mfma_f32_16x16x32_bf16(ya[1], hb1, zy, 0,0,0); \
            if ((TT) > 0 && hi == 0)                                          \
                y_out[(long)(b0 + lo) * T + ((TT) - 1)] = zy[0];              \
        }                                                                     \
        if (CORR) {                                                           \
            _Pragma("unroll")                                                 \
            for (int r = 0; r < 4; ++r) { z0[r] -= corr[0][r]; z1[r] -= corr[1][r]; } \
        }                                                                     \
        float iA = sigm(z0[0]), fA = sigm(z0[1]);                             \
        float gA = tanh_(z0[2]), oA = sigm(z0[3]);                            \
        float iB = sigm(z1[0]), fB = sigm(z1[1]);                             \
        float gB = tanh_(z1[2]), oB = sigm(z1[3]);                            \
        float cnA = fA * csA + iA * gA;                                       \
        float cnB = fB * csB + iB * gB;                                       \
        float hnA = oA * tanh_(cnA);                                          \
        float hnB = oB * tanh_(cnB);                                          \
        csA = cnA; csB = cnB;                                                 \
        unsigned up = pk_bf16(hnA, hnB);                                      \
        hX[(P) ^ 1][lo][unitA] = (unsigned short)up;                          \
        hX[(P) ^ 1][lo][unitB] = (unsigned short)(up >> 16);                  \
        lds_barrier();                                                        \
    }

    DSTEP(0, 1, 0) DSTEP(1, 0, 1) DSTEP(0, 0, 2) DSTEP(1, 0, 3)
    for (int t = 4; t < T; t += 4) {
        DSTEP(0, 0, t) DSTEP(1, 0, t + 1) DSTEP(0, 0, t + 2) DSTEP(1, 0, t + 3)
    }
#undef DSTEP

    if (w == 0) {       // final y_{T-1} (T even -> parity 0)
        short8 hb0 = *(const short8*)&hX[0][lo][hi * 8];
        short8 hb1 = *(const short8*)&hX[0][lo][32 + hi * 8];
        f32x4 zy = {outb_s, outb_s, outb_s, outb_s};
        zy = __builtin_amdgcn_mfma_f32_16x16x32_bf16(ya[0], hb0, zy, 0,0,0);
        zy = __builtin_amdgcn_mfma_f32_16x16x32_bf16(ya[1], hb1, zy, 0,0,0);
        if (hi == 0) y_out[(long)(b0 + lo) * T + (T - 1)] = zy[0];
    }
}

// ---------------------------------------------------------------------------
extern "C" __global__ void __launch_bounds__(256)
loss_kernel(const float* __restrict__ padded, const float* __restrict__ y,
            const int* __restrict__ seq_len, float* __restrict__ acc2)
{
    const long n4 = (long)B * T / 4;
    long i0 = (long)(blockIdx.x * blockDim.x + threadIdx.x);
    long stride = (long)gridDim.x * blockDim.x;
    float s = 0.f, cnt = 0.f;
    for (long i = i0; i < n4; i += stride) {
        int b = (int)(i >> 9);                  // T/4 = 512
        int t = (int)(i & 511) * 4;
        int len = seq_len[b];
        f32x4 pv = *(const f32x4*)&padded[i * 4];
        f32x4 yv = *(const f32x4*)&y[i * 4];
        #pragma unroll
        for (int e = 0; e < 4; ++e)
            if (t + e < len) { float d = pv[e] - yv[e]; s += d * d; cnt += 1.0f; }
    }
    for (int m = 1; m < 64; m <<= 1) { s += __shfl_xor(s, m); cnt += __shfl_xor(cnt, m); }
    if ((threadIdx.x & 63) == 0) { atomicAdd(&acc2[0], s); atomicAdd(&acc2[1], cnt); }
}

extern "C" __global__ void fin_kernel(const float* __restrict__ acc2, float* __restrict__ out)
{
    out[0] = acc2[0] / acc2[1];
}

// ---------------------------------------------------------------------------
extern "C" void kernel_launch(void* const* d_in, const int* in_sizes, int n_in,
                              void* d_out, int out_size, void* d_ws, size_t ws_size,
                              hipStream_t stream)
{
    const float* padded = (const float*)d_in[0];
    const int*   seq    = (const int*)  d_in[1];
    const float* eWih   = (const float*)d_in[2];
    const float* eWhh   = (const float*)d_in[3];
    const float* eb     = (const float*)d_in[4];
    const float* elW    = (const float*)d_in[5];
    const float* elb    = (const float*)d_in[6];
    const float* dlW    = (const float*)d_in[7];
    const float* dlb    = (const float*)d_in[8];
    const float* dWih   = (const float*)d_in[9];
    const float* dWhh   = (const float*)d_in[10];
    const float* db     = (const float*)d_in[11];
    const float* outW   = (const float*)d_in[12];
    const float* outb   = (const float*)d_in[13];
    float* out = (float*)d_out;

    float* ws    = (float*)d_ws;
    float* h_enc = ws;
    float* c_enc = ws + (long)B * H;
    float* hd    = ws + 2L * B * H;
    float* y0c   = ws + 3L * B * H;
    float* acc2  = ws + 3L * B * H + B;

    float* out_pad = out + 1;
    float* out_y   = out + 1 + (long)B * T;
    float* out_hz  = out + 1 + 2L * (long)B * T;

    hipMemcpyAsync(out_pad, padded, (long)B * T * sizeof(float),
                   hipMemcpyDeviceToDevice, stream);
    hipMemsetAsync(acc2, 0, 2 * sizeof(float), stream);

    enc_kernel<<<NB, NTHREADS, 0, stream>>>(padded, seq, eWih, eWhh, eb, h_enc, c_enc);
    mid_kernel<<<B / 256, 256, 0, stream>>>(h_enc, elW, elb, dlW, dlb, outW, outb,
                                            out_hz, hd, y0c);
    dec_kernel<<<NB, NTHREADS, 0, stream>>>(hd, c_enc, dWih, dWhh, db, outW, outb, y0c, out_y);
    loss_kernel<<<1024, 256, 0, stream>>>(padded, out_y, seq, acc2);
    fin_kernel<<<1, 1, 0, stream>>>(acc2, out);
}